// Round 17
// baseline (8861.963 us; speedup 1.0000x reference)
//
#include <hip/hip_runtime.h>
#include <math.h>

constexpr int   P      = 16;   // N_POINTS
constexpr int   DIN    = 48;   // P*3
constexpr int   DH     = 64;   // hidden dim
constexpr int   NITER  = 8;    // I
constexpr int   NLAYER = 2;    // L
constexpr float BIGV   = 1e9f;
constexpr float INV_R  = 1.0f / 2.5f;
constexpr int   RLOG   = 20;   // fast path requires R == 1<<20

typedef float f32x4 __attribute__((ext_vector_type(4)));

// Collapsed input-layer operator: U[c][d] = sum_p W_in[3p+c, d],
// V[c][d] = sum_p t_p * W_in[3p+c, d]. Rows 0..2 = U, 3..5 = V.
__device__ __align__(16) float g_uv[6 * DH];

// monotonic float<->uint key map (total order)
__device__ __forceinline__ unsigned fkey(float f) {
    unsigned b = __float_as_uint(f);
    return (b & 0x80000000u) ? ~b : (b | 0x80000000u);
}
__device__ __forceinline__ float funkey(unsigned k) {
    unsigned b = (k & 0x80000000u) ? (k ^ 0x80000000u) : ~k;
    return __uint_as_float(b);
}

// ---------------------------------------------------------------------------
// SLOW PATH (rare): correctly-rounded f32 elementwise, f64 reductions.
// Verbatim from all passing rounds (computes the TRUE reference value).
// ---------------------------------------------------------------------------
__device__ __noinline__
void slow_eval(const float* __restrict__ orig, const float* __restrict__ vec,
               const float* __restrict__ t1,   const float* __restrict__ t2,
               size_t tidx, unsigned r,
               const float* __restrict__ W_in,  const float* __restrict__ b_in,
               const float* __restrict__ ln_g,  const float* __restrict__ ln_b,
               const float* __restrict__ W_mid, const float* __restrict__ b_mid,
               const float* __restrict__ W_cls, const float* __restrict__ b_cls,
               const float* __restrict__ W_dist,const float* __restrict__ b_dist,
               float& cls_o, float& dval_o)
{
    const float o0 = orig[3*r+0], o1 = orig[3*r+1], o2 = orig[3*r+2];
    const float v0 = vec[3*r+0],  v1 = vec[3*r+1],  v2 = vec[3*r+2];
    const float t1i = t1[tidx], t2i = t2[tidx];

    const float dt  = __fsub_rn(t2i, t1i);
    const float io0 = __fadd_rn(o0, __fmul_rn(v0, t1i));
    const float io1 = __fadd_rn(o1, __fmul_rn(v1, t1i));
    const float io2 = __fadd_rn(o2, __fmul_rn(v2, t1i));
    const float iv0 = __fmul_rn(v0, dt);
    const float iv1 = __fmul_rn(v1, dt);
    const float iv2 = __fmul_rn(v2, dt);
    const float delta = 1.0f / 15.0f;

    float x[DIN];
    #pragma unroll
    for (int p = 0; p < P; ++p) {
        const float tp = __fmul_rn((float)p, delta);
        x[3*p+0] = __fdiv_rn(__fadd_rn(io0, __fmul_rn(iv0, tp)), 2.5f);
        x[3*p+1] = __fdiv_rn(__fadd_rn(io1, __fmul_rn(iv1, tp)), 2.5f);
        x[3*p+2] = __fdiv_rn(__fadd_rn(io2, __fmul_rn(iv2, tp)), 2.5f);
    }

    float a[DH];
    #pragma unroll 1
    for (int d = 0; d < DH; ++d) {
        double acc0 = 0.0, acc1 = 0.0;
        #pragma unroll
        for (int k = 0; k < DIN; k += 2) {
            acc0 = fma((double)x[k],   (double)W_in[k*DH + d],     acc0);
            acc1 = fma((double)x[k+1], (double)W_in[(k+1)*DH + d], acc1);
        }
        a[d] = __fadd_rn((float)(acc0 + acc1), b_in[d]);
    }

    #pragma unroll 1
    for (int l = 0; l < NLAYER; ++l) {
        #pragma unroll 1
        for (int d = 0; d < DH; ++d) a[d] = fmaxf(a[d], 0.0f);

        double s = 0.0;
        #pragma unroll 1
        for (int d = 0; d < DH; ++d) s += (double)a[d];
        const float mu = (float)(s * (1.0 / 64.0));

        double vs = 0.0;
        #pragma unroll 1
        for (int d = 0; d < DH; ++d) {
            const float c = __fsub_rn(a[d], mu);
            vs = fma((double)c, (double)c, vs);
        }
        const float var = (float)(vs * (1.0 / 64.0));
        const float ve  = __fadd_rn(var, 1e-5f);
        const float inv = (float)(1.0 / sqrt((double)ve));

        float hn[DH];
        #pragma unroll 1
        for (int d = 0; d < DH; ++d) {
            float t = __fsub_rn(a[d], mu);
            t = __fmul_rn(t, inv);
            t = __fmul_rn(t, ln_g[l*DH + d]);
            hn[d] = __fadd_rn(t, ln_b[l*DH + d]);
        }

        #pragma unroll 1
        for (int d = 0; d < DH; ++d) {
            double acc0 = 0.0, acc1 = 0.0;
            #pragma unroll
            for (int k = 0; k < DH; k += 2) {
                acc0 = fma((double)hn[k],   (double)W_mid[(l*DH + k)*DH + d],   acc0);
                acc1 = fma((double)hn[k+1], (double)W_mid[(l*DH + k+1)*DH + d], acc1);
            }
            a[d] = __fadd_rn((float)(acc0 + acc1), b_mid[l*DH + d]);
        }
    }

    double c0 = 0.0, c1 = 0.0, d0 = 0.0, d1 = 0.0;
    #pragma unroll 1
    for (int d = 0; d < DH; d += 2) {
        const float h0 = fmaxf(a[d],   0.0f);
        const float h1 = fmaxf(a[d+1], 0.0f);
        c0 = fma((double)h0, (double)W_cls[d],    c0);
        c1 = fma((double)h1, (double)W_cls[d+1],  c1);
        d0 = fma((double)h0, (double)W_dist[d],   d0);
        d1 = fma((double)h1, (double)W_dist[d+1], d1);
    }
    const float cls = __fadd_rn((float)(c0 + c1), b_cls[0]);
    const float dv  = __fadd_rn((float)(d0 + d1), b_dist[0]);
    cls_o  = cls;
    dval_o = __fadd_rn(__fmul_rn(dv, dt), t1i);
}

// ---------------------------------------------------------------------------
// Compaction (one atomic per block, validated R14/R15/R16), init, finalize.
// ---------------------------------------------------------------------------
__global__ __launch_bounds__(256)
void compact_k(const int* __restrict__ mask, unsigned* __restrict__ cnt,
               unsigned* __restrict__ work)
{
    __shared__ unsigned wcnt[4];
    __shared__ unsigned woff[4];

    const int tid  = threadIdx.x;
    const int lane = tid & 63;
    const int wv   = tid >> 6;
    const int idx  = blockIdx.x * 256 + tid;

    const bool m = (mask[idx] != 0);
    const unsigned long long b = __ballot(m);
    const int nact = __popcll(b);
    if (lane == 0) wcnt[wv] = (unsigned)nact;
    __syncthreads();
    if (tid == 0) {
        const unsigned tot = wcnt[0] + wcnt[1] + wcnt[2] + wcnt[3];
        unsigned base = tot ? atomicAdd(cnt, tot) : 0u;
        #pragma unroll
        for (int w = 0; w < 4; ++w) { woff[w] = base; base += wcnt[w]; }
    }
    __syncthreads();
    if (m) {
        const int pre = __popcll(b & ((1ull << lane) - 1ull));
        work[woff[wv] + pre] = (unsigned)idx;
    }
}

__global__ __launch_bounds__(256)
void init_k(unsigned* __restrict__ arena, int R)
{
    const unsigned key_big = fkey(BIGV);
    for (int r = blockIdx.x * 256 + threadIdx.x; r < R; r += gridDim.x * 256)
        arena[r] = key_big;
}

__global__ __launch_bounds__(256)
void finalize_k(float* __restrict__ out, int R)
{
    unsigned* arena = (unsigned*)out + R;
    for (int r = blockIdx.x * 256 + threadIdx.x; r < R; r += gridDim.x * 256) {
        const float dist = funkey(arena[r]);
        const float dfin = (dist == BIGV) ? 0.0f : dist;
        out[r] = (dfin > 0.0f) ? 1.0f : 0.0f;
        ((float*)arena)[r] = dfin;
    }
}

// ---------------------------------------------------------------------------
// Prep: collapsed input operator U,V (validated R15/R16, absmax 0.0078).
// ---------------------------------------------------------------------------
__global__ __launch_bounds__(256)
void prepuv_k(const float* __restrict__ W_in)
{
    const int id = blockIdx.x * 256 + threadIdx.x;
    if (id >= 6 * DH) return;
    const int c  = id / DH;         // 0..5
    const int d  = id % DH;
    const int cc = (c >= 3) ? c - 3 : c;
    const bool isV = (c >= 3);
    float s = 0.0f;
    #pragma unroll
    for (int p = 0; p < P; ++p) {
        const float tp = (float)p * (1.0f / 15.0f);
        const float w  = W_in[(3*p + cc)*DH + d];
        s = isV ? fmaf(tp, w, s) : (s + w);
    }
    g_uv[id] = s;
}

// ---------------------------------------------------------------------------
// MAIN (identical math to R16, which passed): 1 item/lane; weights on the
// scalar SMEM/K$ pipe (wave-uniform compile-time offsets); h register-static
// via k-phase split; h_hi parks in LDS, ONE lgkm burst per layer.
// ONLY change vs R16: __launch_bounds__(256, 1). Evidence across 16 rounds:
// (256,2) caps VGPR at 128 (spilled: 243 MB scratch); (256,1) lets the
// allocator take ~160-200 and it has NEVER spilled there (R6/R12). 2
// waves/SIMD suffices here because the inner loop has no per-k vector-
// memory ops (unlike R13) — only the scalar weight stream.
// ---------------------------------------------------------------------------
__global__ __launch_bounds__(256, 1)
void main1_k(const float* __restrict__ orig,
             const float* __restrict__ vec,
             const float* __restrict__ t1,
             const float* __restrict__ t2,
             const float* __restrict__ W_in,
             const float* __restrict__ b_in,
             const float* __restrict__ ln_g,
             const float* __restrict__ ln_b,
             const float* __restrict__ W_mid,
             const float* __restrict__ b_mid,
             const float* __restrict__ W_cls,
             const float* __restrict__ b_cls,
             const float* __restrict__ W_dist,
             const float* __restrict__ b_dist,
             const unsigned* __restrict__ work,
             const unsigned* __restrict__ cnt,
             unsigned* __restrict__ arena)
{
    __shared__ float park[4][32][64];   // 32 KiB: h[32..63] per lane

    const int tid  = threadIdx.x;
    const int lane = tid & 63;
    const int wv   = tid >> 6;

    float* col = &park[wv][0][lane];    // element j lives at col[j*64]

    const unsigned T    = *cnt;
    const unsigned gtid = blockIdx.x * 256 + tid;
    const unsigned NTOT = gridDim.x * 256;

    #pragma unroll 1
    for (unsigned g = gtid; g < T; g += NTOT) {
        const unsigned pk = work[g];
        const unsigned r  = pk & 0xFFFFFu;
        const float tt1 = t1[pk], tt2 = t2[pk];
        const float dt  = tt2 - tt1;
        const float o0 = orig[3*r+0], o1 = orig[3*r+1], o2 = orig[3*r+2];
        const float v0 = vec[3*r+0],  v1 = vec[3*r+1],  v2 = vec[3*r+2];
        const float io0 = fmaf(v0, tt1, o0);
        const float io1 = fmaf(v1, tt1, o1);
        const float io2 = fmaf(v2, tt1, o2);
        const float iv0 = v0 * dt, iv1 = v1 * dt, iv2 = v2 * dt;

        float a[DH];

        // ---- input layer, collapsed: a = INV_R*(io.U + iv.V) + b_in
        #pragma unroll
        for (int d = 0; d < DH; ++d) {
            float s = io0 * g_uv[0*DH + d];
            s = fmaf(io1, g_uv[1*DH + d], s);
            s = fmaf(io2, g_uv[2*DH + d], s);
            s = fmaf(iv0, g_uv[3*DH + d], s);
            s = fmaf(iv1, g_uv[4*DH + d], s);
            s = fmaf(iv2, g_uv[5*DH + d], s);
            a[d] = fmaf(s, INV_R, b_in[d]);
        }

        float invprod = 1.0f;

        // ---- mid layers (rolled; hot code L1I-resident)
        #pragma unroll 1
        for (int l = 0; l < NLAYER; ++l) {
            #pragma unroll
            for (int d = 0; d < DH; ++d) a[d] = fmaxf(a[d], 0.0f);

            float mu = 0.0f;
            #pragma unroll
            for (int d = 0; d < DH; ++d) mu += a[d];
            mu *= (1.0f / 64.0f);

            float var = 0.0f;
            #pragma unroll
            for (int d = 0; d < DH; ++d) {
                const float c = a[d] - mu;
                var = fmaf(c, c, var);
            }
            var *= (1.0f / 64.0f);
            const float inv = 1.0f / sqrtf(var + 1e-5f);
            invprod *= inv;

            const float* gg = ln_g + l*DH;
            const float* bb = ln_b + l*DH;

            // h_lo (k=0..31): transform a[0..31] IN PLACE (stays in regs)
            #pragma unroll
            for (int d = 0; d < 32; ++d)
                a[d] = fmaf((a[d] - mu) * inv, gg[d], bb[d]);
            // h_hi (k=32..63): compute and park in LDS; a[32..63] then dead
            #pragma unroll
            for (int d = 32; d < DH; ++d)
                col[(d-32)*64] = fmaf((a[d] - mu) * inv, gg[d], bb[d]);

            float acc2[DH];
            #pragma unroll
            for (int d = 0; d < DH; ++d) acc2[d] = 0.0f;

            const float* Wl = W_mid + l*DH*DH;   // uniform base

            // phase A: k = 0..31, h static in a[k] — SGPR-weight FMAs
            #pragma unroll
            for (int k = 0; k < 32; ++k) {
                const float hk = a[k];
                const f32x4* wr = (const f32x4*)(Wl + k*DH);
                #pragma unroll
                for (int j = 0; j < 16; ++j) {
                    const f32x4 w4 = wr[j];
                    acc2[4*j+0] = fmaf(hk, w4.x, acc2[4*j+0]);
                    acc2[4*j+1] = fmaf(hk, w4.y, acc2[4*j+1]);
                    acc2[4*j+2] = fmaf(hk, w4.z, acc2[4*j+2]);
                    acc2[4*j+3] = fmaf(hk, w4.w, acc2[4*j+3]);
                }
            }

            // burst-unpark h_hi into the (dead) a[0..31] registers:
            // ONE lgkmcnt drain per layer, not per k.
            #pragma unroll
            for (int j = 0; j < 32; ++j)
                a[j] = col[j*64];

            // phase B: k = 32..63
            #pragma unroll
            for (int k = 32; k < DH; ++k) {
                const float hk = a[k-32];
                const f32x4* wr = (const f32x4*)(Wl + k*DH);
                #pragma unroll
                for (int j = 0; j < 16; ++j) {
                    const f32x4 w4 = wr[j];
                    acc2[4*j+0] = fmaf(hk, w4.x, acc2[4*j+0]);
                    acc2[4*j+1] = fmaf(hk, w4.y, acc2[4*j+1]);
                    acc2[4*j+2] = fmaf(hk, w4.z, acc2[4*j+2]);
                    acc2[4*j+3] = fmaf(hk, w4.w, acc2[4*j+3]);
                }
            }

            const float* bm = b_mid + l*DH;
            #pragma unroll
            for (int d = 0; d < DH; ++d) a[d] = acc2[d] + bm[d];
        }

        // ---- heads (4 chains each; weights uniform -> scalar)
        #pragma unroll
        for (int d = 0; d < DH; ++d) a[d] = fmaxf(a[d], 0.0f);

        float c0 = 0.f, c1 = 0.f, c2 = 0.f, c3 = 0.f;
        float e0 = 0.f, e1 = 0.f, e2 = 0.f, e3 = 0.f;
        #pragma unroll
        for (int j = 0; j < 16; ++j) {
            c0 = fmaf(a[4*j+0], W_cls[4*j+0],  c0);
            c1 = fmaf(a[4*j+1], W_cls[4*j+1],  c1);
            c2 = fmaf(a[4*j+2], W_cls[4*j+2],  c2);
            c3 = fmaf(a[4*j+3], W_cls[4*j+3],  c3);
            e0 = fmaf(a[4*j+0], W_dist[4*j+0], e0);
            e1 = fmaf(a[4*j+1], W_dist[4*j+1], e1);
            e2 = fmaf(a[4*j+2], W_dist[4*j+2], e2);
            e3 = fmaf(a[4*j+3], W_dist[4*j+3], e3);
        }
        float cls = ((c0 + c1) + (c2 + c3)) + b_cls[0];
        float dv  = ((e0 + e1) + (e2 + e3)) + b_dist[0];
        float dval = fmaf(dv, dt, tt1);

        // borderline guard (floor 3e-4 — validated with U,V collapse)
        float thr = 2e-6f * invprod;
        thr = fminf(fmaxf(thr, 3e-4f), 2e-2f);
        if ((fabsf(cls) < thr) || (fabsf(dval) < thr)) {
            slow_eval(orig, vec, t1, t2, (size_t)pk, r,
                      W_in, b_in, ln_g, ln_b, W_mid, b_mid,
                      W_cls, b_cls, W_dist, b_dist, cls, dval);
        }
        if (cls > 0.0f)
            atomicMin(arena + r, fkey(dval));
    }
}

// ---------------------------------------------------------------------------
// FALLBACK (round-5 kernel, known-good) for unexpected R / small workspace.
// ---------------------------------------------------------------------------
__global__ __launch_bounds__(256, 2)
void fallback_k(const float* __restrict__ orig, const float* __restrict__ vec,
                const float* __restrict__ t1,   const float* __restrict__ t2,
                const int*   __restrict__ mask,
                const float* __restrict__ W_in,  const float* __restrict__ b_in,
                const float* __restrict__ ln_g,  const float* __restrict__ ln_b,
                const float* __restrict__ W_mid, const float* __restrict__ b_mid,
                const float* __restrict__ W_cls, const float* __restrict__ b_cls,
                const float* __restrict__ W_dist,const float* __restrict__ b_dist,
                float* __restrict__ out, int R)
{
    __shared__ __align__(16) float wlds[DIN*DH + NLAYER*DH*DH];
    __shared__ __align__(16) float act[4][32][64];

    const int tid  = threadIdx.x;
    const int lane = tid & 63;
    const int wv   = tid >> 6;

    {
        f32x4*       dst = (f32x4*)wlds;
        const f32x4* s1  = (const f32x4*)W_in;
        const f32x4* s2  = (const f32x4*)W_mid;
        #pragma unroll 1
        for (int idx = tid; idx < DIN*DH/4; idx += 256)        dst[idx] = s1[idx];
        #pragma unroll 1
        for (int idx = tid; idx < NLAYER*DH*DH/4; idx += 256)  dst[DIN*DH/4 + idx] = s2[idx];
    }
    __syncthreads();

    const float* win_l  = wlds;
    const float* wmid_l = wlds + DIN*DH;

    const int r = blockIdx.x * 256 + tid;
    if (r >= R) return;

    float* myact = &act[wv][0][lane];

    const float o0 = orig[3*r+0], o1 = orig[3*r+1], o2 = orig[3*r+2];
    const float v0 = vec[3*r+0],  v1 = vec[3*r+1],  v2 = vec[3*r+2];

    float dist = BIGV;

    #pragma unroll 1
    for (int i = 0; i < NITER; ++i) {
        const float t1i = t1[(size_t)i * R + r];
        const float t2i = t2[(size_t)i * R + r];
        const int   mi  = mask[(size_t)i * R + r];
        if (!mi) continue;
        const float dt = t2i - t1i;

        const float io0 = fmaf(v0, t1i, o0);
        const float io1 = fmaf(v1, t1i, o1);
        const float io2 = fmaf(v2, t1i, o2);
        const float iv0 = v0 * dt, iv1 = v1 * dt, iv2 = v2 * dt;

        float a[DH];
        #pragma unroll
        for (int d = 0; d < DH; ++d) a[d] = 0.0f;

        #pragma unroll 1
        for (int p = 0; p < P; ++p) {
            const float tp = (float)p * (1.0f / 15.0f);
            const float x0 = fmaf(iv0, tp, io0) * INV_R;
            const float x1 = fmaf(iv1, tp, io1) * INV_R;
            const float x2 = fmaf(iv2, tp, io2) * INV_R;
            const f32x4* w0 = (const f32x4*)(win_l + (3*p+0)*DH);
            const f32x4* w1 = (const f32x4*)(win_l + (3*p+1)*DH);
            const f32x4* w2 = (const f32x4*)(win_l + (3*p+2)*DH);
            #pragma unroll
            for (int j = 0; j < 16; ++j) {
                const f32x4 u = w0[j], v4 = w1[j], w4 = w2[j];
                a[4*j+0] = fmaf(x2, w4.x, fmaf(x1, v4.x, fmaf(x0, u.x, a[4*j+0])));
                a[4*j+1] = fmaf(x2, w4.y, fmaf(x1, v4.y, fmaf(x0, u.y, a[4*j+1])));
                a[4*j+2] = fmaf(x2, w4.z, fmaf(x1, v4.z, fmaf(x0, u.z, a[4*j+2])));
                a[4*j+3] = fmaf(x2, w4.w, fmaf(x1, v4.w, fmaf(x0, u.w, a[4*j+3])));
            }
        }
        #pragma unroll
        for (int d = 0; d < DH; ++d) a[d] += b_in[d];

        float invprod = 1.0f;

        #pragma unroll 1
        for (int l = 0; l < NLAYER; ++l) {
            #pragma unroll
            for (int d = 0; d < DH; ++d) a[d] = fmaxf(a[d], 0.0f);

            float mu = 0.0f;
            #pragma unroll
            for (int d = 0; d < DH; ++d) mu += a[d];
            mu *= (1.0f / 64.0f);

            float var = 0.0f;
            #pragma unroll
            for (int d = 0; d < DH; ++d) {
                const float cdev = a[d] - mu;
                var = fmaf(cdev, cdev, var);
            }
            var *= (1.0f / 64.0f);
            const float inv = 1.0f / sqrtf(var + 1e-5f);
            invprod *= inv;

            const float* gp = ln_g + l*DH;
            const float* bp = ln_b + l*DH;

            #pragma unroll
            for (int d = 0; d < 32; ++d)
                myact[d*64] = fmaf((a[d] - mu) * inv, gp[d], bp[d]);
            float hh[32];
            #pragma unroll
            for (int j = 0; j < 32; ++j)
                hh[j] = fmaf((a[32+j] - mu) * inv, gp[32+j], bp[32+j]);

            #pragma unroll
            for (int d = 0; d < DH; ++d) a[d] = 0.0f;

            const float* Wl = wmid_l + l*DH*DH;
            #pragma unroll 4
            for (int k = 0; k < 32; ++k) {
                const float hk = myact[k*64];
                const f32x4* wr = (const f32x4*)(Wl + k*DH);
                #pragma unroll
                for (int j = 0; j < 16; ++j) {
                    const f32x4 w4 = wr[j];
                    a[4*j+0] = fmaf(hk, w4.x, a[4*j+0]);
                    a[4*j+1] = fmaf(hk, w4.y, a[4*j+1]);
                    a[4*j+2] = fmaf(hk, w4.z, a[4*j+2]);
                    a[4*j+3] = fmaf(hk, w4.w, a[4*j+3]);
                }
            }
            #pragma unroll
            for (int j = 0; j < 32; ++j)
                myact[j*64] = hh[j];
            #pragma unroll 4
            for (int k = 32; k < DH; ++k) {
                const float hk = myact[(k-32)*64];
                const f32x4* wr = (const f32x4*)(Wl + k*DH);
                #pragma unroll
                for (int j = 0; j < 16; ++j) {
                    const f32x4 w4 = wr[j];
                    a[4*j+0] = fmaf(hk, w4.x, a[4*j+0]);
                    a[4*j+1] = fmaf(hk, w4.y, a[4*j+1]);
                    a[4*j+2] = fmaf(hk, w4.z, a[4*j+2]);
                    a[4*j+3] = fmaf(hk, w4.w, a[4*j+3]);
                }
            }
            const float* bm = b_mid + l*DH;
            #pragma unroll
            for (int d = 0; d < DH; ++d) a[d] += bm[d];
        }

        #pragma unroll
        for (int d = 0; d < DH; ++d) a[d] = fmaxf(a[d], 0.0f);

        float c0 = 0.f, c1 = 0.f, c2 = 0.f, c3 = 0.f;
        float e0 = 0.f, e1 = 0.f, e2 = 0.f, e3 = 0.f;
        #pragma unroll
        for (int j = 0; j < 16; ++j) {
            c0 = fmaf(a[4*j+0], W_cls[4*j+0],  c0);
            c1 = fmaf(a[4*j+1], W_cls[4*j+1],  c1);
            c2 = fmaf(a[4*j+2], W_cls[4*j+2],  c2);
            c3 = fmaf(a[4*j+3], W_cls[4*j+3],  c3);
            e0 = fmaf(a[4*j+0], W_dist[4*j+0], e0);
            e1 = fmaf(a[4*j+1], W_dist[4*j+1], e1);
            e2 = fmaf(a[4*j+2], W_dist[4*j+2], e2);
            e3 = fmaf(a[4*j+3], W_dist[4*j+3], e3);
        }
        float cls = ((c0 + c1) + (c2 + c3)) + b_cls[0];
        float dv  = ((e0 + e1) + (e2 + e3)) + b_dist[0];
        float dval = fmaf(dv, dt, t1i);

        float thr = 2e-6f * invprod;
        thr = fminf(fmaxf(thr, 3e-5f), 2e-2f);
        if ((fabsf(cls) < thr) || (fabsf(dval) < thr)) {
            slow_eval(orig, vec, t1, t2, (size_t)i * R + r, (unsigned)r,
                      W_in, b_in, ln_g, ln_b, W_mid, b_mid,
                      W_cls, b_cls, W_dist, b_dist, cls, dval);
        }

        if (cls > 0.0f && dval < dist) dist = dval;
    }

    const float dfin = (dist == BIGV) ? 0.0f : dist;
    out[r]     = (dfin > 0.0f) ? 1.0f : 0.0f;
    out[R + r] = dfin;
}

extern "C" void kernel_launch(void* const* d_in, const int* in_sizes, int n_in,
                              void* d_out, int out_size, void* d_ws, size_t ws_size,
                              hipStream_t stream) {
    const float* orig   = (const float*)d_in[0];
    const float* vec    = (const float*)d_in[1];
    const float* t1     = (const float*)d_in[2];
    const float* t2     = (const float*)d_in[3];
    const int*   mask   = (const int*)  d_in[4];
    const float* W_in   = (const float*)d_in[5];
    const float* b_in   = (const float*)d_in[6];
    const float* ln_g   = (const float*)d_in[7];
    const float* ln_b   = (const float*)d_in[8];
    const float* W_mid  = (const float*)d_in[9];
    const float* b_mid  = (const float*)d_in[10];
    const float* W_cls  = (const float*)d_in[11];
    const float* b_cls  = (const float*)d_in[12];
    const float* W_dist = (const float*)d_in[13];
    const float* b_dist = (const float*)d_in[14];

    float* out = (float*)d_out;
    const int R = in_sizes[0] / 3;

    const size_t need_ws = 16 + 4ull * (size_t)R * NITER;
    const bool fast = (R == (1 << RLOG)) && (ws_size >= need_ws);

    if (fast) {
        unsigned* cnt   = (unsigned*)d_ws;
        unsigned* work  = (unsigned*)d_ws + 4;   // 16B offset
        unsigned* arena = (unsigned*)d_out + R;  // out[R..2R) as key arena

        hipMemsetAsync(cnt, 0, 4, stream);
        compact_k<<<(R * NITER) / 256, 256, 0, stream>>>(mask, cnt, work);
        prepuv_k<<<2, 256, 0, stream>>>(W_in);
        init_k<<<1024, 256, 0, stream>>>(arena, R);
        main1_k<<<2048, 256, 0, stream>>>(orig, vec, t1, t2,
                                          W_in, b_in, ln_g, ln_b, W_mid, b_mid,
                                          W_cls, b_cls, W_dist, b_dist,
                                          work, cnt, arena);
        finalize_k<<<1024, 256, 0, stream>>>(out, R);
    } else {
        const int threads = 256;
        const int blocks  = (R + threads - 1) / threads;
        fallback_k<<<blocks, threads, 0, stream>>>(
            orig, vec, t1, t2, mask,
            W_in, b_in, ln_g, ln_b, W_mid, b_mid,
            W_cls, b_cls, W_dist, b_dist,
            out, R);
    }
}

// Round 18
// 7997.563 us; speedup vs baseline: 1.1081x; 1.1081x over previous
//
#include <hip/hip_runtime.h>
#include <math.h>

constexpr int   P      = 16;   // N_POINTS
constexpr int   DIN    = 48;   // P*3
constexpr int   DH     = 64;   // hidden dim
constexpr int   NITER  = 8;    // I
constexpr int   NLAYER = 2;    // L
constexpr float BIGV   = 1e9f;
constexpr float INV_R  = 1.0f / 2.5f;
constexpr int   RLOG   = 20;   // fast path requires R == 1<<20

typedef float f32x4 __attribute__((ext_vector_type(4)));

// Collapsed input-layer operator: U[c][d] = sum_p W_in[3p+c, d],
// V[c][d] = sum_p t_p * W_in[3p+c, d]. Rows 0..2 = U, 3..5 = V.
__device__ __align__(16) float g_uv[6 * DH];

// monotonic float<->uint key map (total order)
__device__ __forceinline__ unsigned fkey(float f) {
    unsigned b = __float_as_uint(f);
    return (b & 0x80000000u) ? ~b : (b | 0x80000000u);
}
__device__ __forceinline__ float funkey(unsigned k) {
    unsigned b = (k & 0x80000000u) ? (k ^ 0x80000000u) : ~k;
    return __uint_as_float(b);
}

// ---------------------------------------------------------------------------
// SLOW PATH (rare): correctly-rounded f32 elementwise, f64 reductions.
// Verbatim from all passing rounds (computes the TRUE reference value).
// ---------------------------------------------------------------------------
__device__ __noinline__
void slow_eval(const float* __restrict__ orig, const float* __restrict__ vec,
               const float* __restrict__ t1,   const float* __restrict__ t2,
               size_t tidx, unsigned r,
               const float* __restrict__ W_in,  const float* __restrict__ b_in,
               const float* __restrict__ ln_g,  const float* __restrict__ ln_b,
               const float* __restrict__ W_mid, const float* __restrict__ b_mid,
               const float* __restrict__ W_cls, const float* __restrict__ b_cls,
               const float* __restrict__ W_dist,const float* __restrict__ b_dist,
               float& cls_o, float& dval_o)
{
    const float o0 = orig[3*r+0], o1 = orig[3*r+1], o2 = orig[3*r+2];
    const float v0 = vec[3*r+0],  v1 = vec[3*r+1],  v2 = vec[3*r+2];
    const float t1i = t1[tidx], t2i = t2[tidx];

    const float dt  = __fsub_rn(t2i, t1i);
    const float io0 = __fadd_rn(o0, __fmul_rn(v0, t1i));
    const float io1 = __fadd_rn(o1, __fmul_rn(v1, t1i));
    const float io2 = __fadd_rn(o2, __fmul_rn(v2, t1i));
    const float iv0 = __fmul_rn(v0, dt);
    const float iv1 = __fmul_rn(v1, dt);
    const float iv2 = __fmul_rn(v2, dt);
    const float delta = 1.0f / 15.0f;

    float x[DIN];
    #pragma unroll
    for (int p = 0; p < P; ++p) {
        const float tp = __fmul_rn((float)p, delta);
        x[3*p+0] = __fdiv_rn(__fadd_rn(io0, __fmul_rn(iv0, tp)), 2.5f);
        x[3*p+1] = __fdiv_rn(__fadd_rn(io1, __fmul_rn(iv1, tp)), 2.5f);
        x[3*p+2] = __fdiv_rn(__fadd_rn(io2, __fmul_rn(iv2, tp)), 2.5f);
    }

    float a[DH];
    #pragma unroll 1
    for (int d = 0; d < DH; ++d) {
        double acc0 = 0.0, acc1 = 0.0;
        #pragma unroll
        for (int k = 0; k < DIN; k += 2) {
            acc0 = fma((double)x[k],   (double)W_in[k*DH + d],     acc0);
            acc1 = fma((double)x[k+1], (double)W_in[(k+1)*DH + d], acc1);
        }
        a[d] = __fadd_rn((float)(acc0 + acc1), b_in[d]);
    }

    #pragma unroll 1
    for (int l = 0; l < NLAYER; ++l) {
        #pragma unroll 1
        for (int d = 0; d < DH; ++d) a[d] = fmaxf(a[d], 0.0f);

        double s = 0.0;
        #pragma unroll 1
        for (int d = 0; d < DH; ++d) s += (double)a[d];
        const float mu = (float)(s * (1.0 / 64.0));

        double vs = 0.0;
        #pragma unroll 1
        for (int d = 0; d < DH; ++d) {
            const float c = __fsub_rn(a[d], mu);
            vs = fma((double)c, (double)c, vs);
        }
        const float var = (float)(vs * (1.0 / 64.0));
        const float ve  = __fadd_rn(var, 1e-5f);
        const float inv = (float)(1.0 / sqrt((double)ve));

        float hn[DH];
        #pragma unroll 1
        for (int d = 0; d < DH; ++d) {
            float t = __fsub_rn(a[d], mu);
            t = __fmul_rn(t, inv);
            t = __fmul_rn(t, ln_g[l*DH + d]);
            hn[d] = __fadd_rn(t, ln_b[l*DH + d]);
        }

        #pragma unroll 1
        for (int d = 0; d < DH; ++d) {
            double acc0 = 0.0, acc1 = 0.0;
            #pragma unroll
            for (int k = 0; k < DH; k += 2) {
                acc0 = fma((double)hn[k],   (double)W_mid[(l*DH + k)*DH + d],   acc0);
                acc1 = fma((double)hn[k+1], (double)W_mid[(l*DH + k+1)*DH + d], acc1);
            }
            a[d] = __fadd_rn((float)(acc0 + acc1), b_mid[l*DH + d]);
        }
    }

    double c0 = 0.0, c1 = 0.0, d0 = 0.0, d1 = 0.0;
    #pragma unroll 1
    for (int d = 0; d < DH; d += 2) {
        const float h0 = fmaxf(a[d],   0.0f);
        const float h1 = fmaxf(a[d+1], 0.0f);
        c0 = fma((double)h0, (double)W_cls[d],    c0);
        c1 = fma((double)h1, (double)W_cls[d+1],  c1);
        d0 = fma((double)h0, (double)W_dist[d],   d0);
        d1 = fma((double)h1, (double)W_dist[d+1], d1);
    }
    const float cls = __fadd_rn((float)(c0 + c1), b_cls[0]);
    const float dv  = __fadd_rn((float)(d0 + d1), b_dist[0]);
    cls_o  = cls;
    dval_o = __fadd_rn(__fmul_rn(dv, dt), t1i);
}

// ---------------------------------------------------------------------------
// Compaction (one atomic per block, validated R14+), init, finalize.
// ---------------------------------------------------------------------------
__global__ __launch_bounds__(256)
void compact_k(const int* __restrict__ mask, unsigned* __restrict__ cnt,
               unsigned* __restrict__ work)
{
    __shared__ unsigned wcnt[4];
    __shared__ unsigned woff[4];

    const int tid  = threadIdx.x;
    const int lane = tid & 63;
    const int wv   = tid >> 6;
    const int idx  = blockIdx.x * 256 + tid;

    const bool m = (mask[idx] != 0);
    const unsigned long long b = __ballot(m);
    const int nact = __popcll(b);
    if (lane == 0) wcnt[wv] = (unsigned)nact;
    __syncthreads();
    if (tid == 0) {
        const unsigned tot = wcnt[0] + wcnt[1] + wcnt[2] + wcnt[3];
        unsigned base = tot ? atomicAdd(cnt, tot) : 0u;
        #pragma unroll
        for (int w = 0; w < 4; ++w) { woff[w] = base; base += wcnt[w]; }
    }
    __syncthreads();
    if (m) {
        const int pre = __popcll(b & ((1ull << lane) - 1ull));
        work[woff[wv] + pre] = (unsigned)idx;
    }
}

__global__ __launch_bounds__(256)
void init_k(unsigned* __restrict__ arena, int R)
{
    const unsigned key_big = fkey(BIGV);
    for (int r = blockIdx.x * 256 + threadIdx.x; r < R; r += gridDim.x * 256)
        arena[r] = key_big;
}

__global__ __launch_bounds__(256)
void finalize_k(float* __restrict__ out, int R)
{
    unsigned* arena = (unsigned*)out + R;
    for (int r = blockIdx.x * 256 + threadIdx.x; r < R; r += gridDim.x * 256) {
        const float dist = funkey(arena[r]);
        const float dfin = (dist == BIGV) ? 0.0f : dist;
        out[r] = (dfin > 0.0f) ? 1.0f : 0.0f;
        ((float*)arena)[r] = dfin;
    }
}

// ---------------------------------------------------------------------------
// Prep: collapsed input operator U,V (validated R15-R17, absmax 0.0078).
// ---------------------------------------------------------------------------
__global__ __launch_bounds__(256)
void prepuv_k(const float* __restrict__ W_in)
{
    const int id = blockIdx.x * 256 + threadIdx.x;
    if (id >= 6 * DH) return;
    const int c  = id / DH;         // 0..5
    const int d  = id % DH;
    const int cc = (c >= 3) ? c - 3 : c;
    const bool isV = (c >= 3);
    float s = 0.0f;
    #pragma unroll
    for (int p = 0; p < P; ++p) {
        const float tp = (float)p * (1.0f / 15.0f);
        const float w  = W_in[(3*p + cc)*DH + d];
        s = isV ? fmaf(tp, w, s) : (s + w);
    }
    g_uv[id] = s;
}

// ---------------------------------------------------------------------------
// MAIN: 512 threads (8 waves), ONE item/lane. The previously-untested cell:
//  - live set ~105 VGPR < the 512-thread 128-VGPR cap -> NO SPILL by design
//  - 8 waves/CU (LDS 160 KB = W_mid 32 KB + act 128 KB, 1 block/CU) ->
//    enough TLP to drive the LDS pipe (R13's 2-wave latency problem solved)
//  - BOTH W_mid layers broadcast from LDS (cheapest measured weight path:
//    ~26K LDS-cyc per 64-item pass -> ~2.8 ms roofline)
//  - input layer UV-collapsed (no W_in stream at all; guard floor 3e-4)
// Per-item FP sequence: UV input (R15+) + k-sequential full-column matmul
// (R5 family). Same-lane LDS write->read in order; no barriers after stage.
// ---------------------------------------------------------------------------
__global__ __launch_bounds__(512)
void main1_k(const float* __restrict__ orig,
             const float* __restrict__ vec,
             const float* __restrict__ t1,
             const float* __restrict__ t2,
             const float* __restrict__ W_in,
             const float* __restrict__ b_in,
             const float* __restrict__ ln_g,
             const float* __restrict__ ln_b,
             const float* __restrict__ W_mid,
             const float* __restrict__ b_mid,
             const float* __restrict__ W_cls,
             const float* __restrict__ b_cls,
             const float* __restrict__ W_dist,
             const float* __restrict__ b_dist,
             const unsigned* __restrict__ work,
             const unsigned* __restrict__ cnt,
             unsigned* __restrict__ arena)
{
    __shared__ __align__(16) float wlds[NLAYER*DH*DH];  // 32 KiB: both W_mid
    __shared__ float act[8][DH][64];                    // 128 KiB

    const int tid  = threadIdx.x;
    const int lane = tid & 63;
    const int wv   = tid >> 6;

    {   // stage both W_mid layers (whole block), one barrier
        f32x4*       dst = (f32x4*)wlds;
        const f32x4* s2  = (const f32x4*)W_mid;
        #pragma unroll 1
        for (int idx = tid; idx < NLAYER*DH*DH/4; idx += 512) dst[idx] = s2[idx];
    }
    __syncthreads();

    float* col = &act[wv][0][lane];   // element k lives at col[k*64]

    const unsigned T    = *cnt;
    const unsigned gtid = blockIdx.x * 512 + tid;
    const unsigned NTOT = gridDim.x * 512;

    #pragma unroll 1
    for (unsigned g = gtid; g < T; g += NTOT) {
        const unsigned pk = work[g];
        const unsigned r  = pk & 0xFFFFFu;
        const float tt1 = t1[pk], tt2 = t2[pk];
        const float dt  = tt2 - tt1;
        const float o0 = orig[3*r+0], o1 = orig[3*r+1], o2 = orig[3*r+2];
        const float v0 = vec[3*r+0],  v1 = vec[3*r+1],  v2 = vec[3*r+2];
        const float io0 = fmaf(v0, tt1, o0);
        const float io1 = fmaf(v1, tt1, o1);
        const float io2 = fmaf(v2, tt1, o2);
        const float iv0 = v0 * dt, iv1 = v1 * dt, iv2 = v2 * dt;

        float a[DH];

        // ---- input layer, collapsed: a = INV_R*(io.U + iv.V) + b_in
        {
            const f32x4* U0 = (const f32x4*)(g_uv + 0*DH);
            const f32x4* U1 = (const f32x4*)(g_uv + 1*DH);
            const f32x4* U2 = (const f32x4*)(g_uv + 2*DH);
            const f32x4* V0 = (const f32x4*)(g_uv + 3*DH);
            const f32x4* V1 = (const f32x4*)(g_uv + 4*DH);
            const f32x4* V2 = (const f32x4*)(g_uv + 5*DH);
            const f32x4* B  = (const f32x4*)b_in;
            #pragma unroll
            for (int j = 0; j < 16; ++j) {
                const f32x4 u0 = U0[j], u1 = U1[j], u2 = U2[j];
                const f32x4 w0 = V0[j], w1 = V1[j], w2 = V2[j];
                const f32x4 bb = B[j];
                #pragma unroll
                for (int q = 0; q < 4; ++q) {
                    float s = io0 * u0[q];
                    s = fmaf(io1, u1[q], s);
                    s = fmaf(io2, u2[q], s);
                    s = fmaf(iv0, w0[q], s);
                    s = fmaf(iv1, w1[q], s);
                    s = fmaf(iv2, w2[q], s);
                    a[4*j+q] = fmaf(s, INV_R, bb[q]);
                }
            }
        }

        float invprod = 1.0f;

        // ---- mid layers: relu -> LN -> full h column in LDS -> matmul
        #pragma unroll 1
        for (int l = 0; l < NLAYER; ++l) {
            #pragma unroll
            for (int d = 0; d < DH; ++d) a[d] = fmaxf(a[d], 0.0f);

            float mu = 0.0f;
            #pragma unroll
            for (int d = 0; d < DH; ++d) mu += a[d];
            mu *= (1.0f / 64.0f);

            float var = 0.0f;
            #pragma unroll
            for (int d = 0; d < DH; ++d) {
                const float c = a[d] - mu;
                var = fmaf(c, c, var);
            }
            var *= (1.0f / 64.0f);
            const float inv = 1.0f / sqrtf(var + 1e-5f);
            invprod *= inv;

            const float* gg = ln_g + l*DH;
            const float* bb = ln_b + l*DH;

            // full hn column -> LDS (same-lane DS in order; conflict-free)
            #pragma unroll
            for (int d = 0; d < DH; ++d)
                col[d*64] = fmaf((a[d] - mu) * inv, gg[d], bb[d]);

            #pragma unroll
            for (int d = 0; d < DH; ++d) a[d] = 0.0f;

            const float* Wl = wlds + l*DH*DH;   // LDS broadcast rows
            #pragma unroll 2
            for (int k = 0; k < DH; ++k) {
                const float hk = col[k*64];
                const f32x4* wr = (const f32x4*)(Wl + k*DH);
                #pragma unroll
                for (int j = 0; j < 16; ++j) {
                    const f32x4 w4 = wr[j];
                    a[4*j+0] = fmaf(hk, w4.x, a[4*j+0]);
                    a[4*j+1] = fmaf(hk, w4.y, a[4*j+1]);
                    a[4*j+2] = fmaf(hk, w4.z, a[4*j+2]);
                    a[4*j+3] = fmaf(hk, w4.w, a[4*j+3]);
                }
            }
            const float* bm = b_mid + l*DH;
            #pragma unroll
            for (int d = 0; d < DH; ++d) a[d] += bm[d];
        }

        // ---- heads (4 chains each)
        #pragma unroll
        for (int d = 0; d < DH; ++d) a[d] = fmaxf(a[d], 0.0f);

        float c0 = 0.f, c1 = 0.f, c2 = 0.f, c3 = 0.f;
        float e0 = 0.f, e1 = 0.f, e2 = 0.f, e3 = 0.f;
        #pragma unroll
        for (int j = 0; j < 16; ++j) {
            c0 = fmaf(a[4*j+0], W_cls[4*j+0],  c0);
            c1 = fmaf(a[4*j+1], W_cls[4*j+1],  c1);
            c2 = fmaf(a[4*j+2], W_cls[4*j+2],  c2);
            c3 = fmaf(a[4*j+3], W_cls[4*j+3],  c3);
            e0 = fmaf(a[4*j+0], W_dist[4*j+0], e0);
            e1 = fmaf(a[4*j+1], W_dist[4*j+1], e1);
            e2 = fmaf(a[4*j+2], W_dist[4*j+2], e2);
            e3 = fmaf(a[4*j+3], W_dist[4*j+3], e3);
        }
        float cls = ((c0 + c1) + (c2 + c3)) + b_cls[0];
        float dv  = ((e0 + e1) + (e2 + e3)) + b_dist[0];
        float dval = fmaf(dv, dt, tt1);

        // borderline guard (floor 3e-4 — validated with UV collapse)
        float thr = 2e-6f * invprod;
        thr = fminf(fmaxf(thr, 3e-4f), 2e-2f);
        if ((fabsf(cls) < thr) || (fabsf(dval) < thr)) {
            slow_eval(orig, vec, t1, t2, (size_t)pk, r,
                      W_in, b_in, ln_g, ln_b, W_mid, b_mid,
                      W_cls, b_cls, W_dist, b_dist, cls, dval);
        }
        if (cls > 0.0f)
            atomicMin(arena + r, fkey(dval));
    }
}

// ---------------------------------------------------------------------------
// FALLBACK (round-5 kernel, known-good) for unexpected R / small workspace.
// ---------------------------------------------------------------------------
__global__ __launch_bounds__(256, 2)
void fallback_k(const float* __restrict__ orig, const float* __restrict__ vec,
                const float* __restrict__ t1,   const float* __restrict__ t2,
                const int*   __restrict__ mask,
                const float* __restrict__ W_in,  const float* __restrict__ b_in,
                const float* __restrict__ ln_g,  const float* __restrict__ ln_b,
                const float* __restrict__ W_mid, const float* __restrict__ b_mid,
                const float* __restrict__ W_cls, const float* __restrict__ b_cls,
                const float* __restrict__ W_dist,const float* __restrict__ b_dist,
                float* __restrict__ out, int R)
{
    __shared__ __align__(16) float wlds[DIN*DH + NLAYER*DH*DH];
    __shared__ __align__(16) float act[4][32][64];

    const int tid  = threadIdx.x;
    const int lane = tid & 63;
    const int wv   = tid >> 6;

    {
        f32x4*       dst = (f32x4*)wlds;
        const f32x4* s1  = (const f32x4*)W_in;
        const f32x4* s2  = (const f32x4*)W_mid;
        #pragma unroll 1
        for (int idx = tid; idx < DIN*DH/4; idx += 256)        dst[idx] = s1[idx];
        #pragma unroll 1
        for (int idx = tid; idx < NLAYER*DH*DH/4; idx += 256)  dst[DIN*DH/4 + idx] = s2[idx];
    }
    __syncthreads();

    const float* win_l  = wlds;
    const float* wmid_l = wlds + DIN*DH;

    const int r = blockIdx.x * 256 + tid;
    if (r >= R) return;

    float* myact = &act[wv][0][lane];

    const float o0 = orig[3*r+0], o1 = orig[3*r+1], o2 = orig[3*r+2];
    const float v0 = vec[3*r+0],  v1 = vec[3*r+1],  v2 = vec[3*r+2];

    float dist = BIGV;

    #pragma unroll 1
    for (int i = 0; i < NITER; ++i) {
        const float t1i = t1[(size_t)i * R + r];
        const float t2i = t2[(size_t)i * R + r];
        const int   mi  = mask[(size_t)i * R + r];
        if (!mi) continue;
        const float dt = t2i - t1i;

        const float io0 = fmaf(v0, t1i, o0);
        const float io1 = fmaf(v1, t1i, o1);
        const float io2 = fmaf(v2, t1i, o2);
        const float iv0 = v0 * dt, iv1 = v1 * dt, iv2 = v2 * dt;

        float a[DH];
        #pragma unroll
        for (int d = 0; d < DH; ++d) a[d] = 0.0f;

        #pragma unroll 1
        for (int p = 0; p < P; ++p) {
            const float tp = (float)p * (1.0f / 15.0f);
            const float x0 = fmaf(iv0, tp, io0) * INV_R;
            const float x1 = fmaf(iv1, tp, io1) * INV_R;
            const float x2 = fmaf(iv2, tp, io2) * INV_R;
            const f32x4* w0 = (const f32x4*)(win_l + (3*p+0)*DH);
            const f32x4* w1 = (const f32x4*)(win_l + (3*p+1)*DH);
            const f32x4* w2 = (const f32x4*)(win_l + (3*p+2)*DH);
            #pragma unroll
            for (int j = 0; j < 16; ++j) {
                const f32x4 u = w0[j], v4 = w1[j], w4 = w2[j];
                a[4*j+0] = fmaf(x2, w4.x, fmaf(x1, v4.x, fmaf(x0, u.x, a[4*j+0])));
                a[4*j+1] = fmaf(x2, w4.y, fmaf(x1, v4.y, fmaf(x0, u.y, a[4*j+1])));
                a[4*j+2] = fmaf(x2, w4.z, fmaf(x1, v4.z, fmaf(x0, u.z, a[4*j+2])));
                a[4*j+3] = fmaf(x2, w4.w, fmaf(x1, v4.w, fmaf(x0, u.w, a[4*j+3])));
            }
        }
        #pragma unroll
        for (int d = 0; d < DH; ++d) a[d] += b_in[d];

        float invprod = 1.0f;

        #pragma unroll 1
        for (int l = 0; l < NLAYER; ++l) {
            #pragma unroll
            for (int d = 0; d < DH; ++d) a[d] = fmaxf(a[d], 0.0f);

            float mu = 0.0f;
            #pragma unroll
            for (int d = 0; d < DH; ++d) mu += a[d];
            mu *= (1.0f / 64.0f);

            float var = 0.0f;
            #pragma unroll
            for (int d = 0; d < DH; ++d) {
                const float cdev = a[d] - mu;
                var = fmaf(cdev, cdev, var);
            }
            var *= (1.0f / 64.0f);
            const float inv = 1.0f / sqrtf(var + 1e-5f);
            invprod *= inv;

            const float* gp = ln_g + l*DH;
            const float* bp = ln_b + l*DH;

            #pragma unroll
            for (int d = 0; d < 32; ++d)
                myact[d*64] = fmaf((a[d] - mu) * inv, gp[d], bp[d]);
            float hh[32];
            #pragma unroll
            for (int j = 0; j < 32; ++j)
                hh[j] = fmaf((a[32+j] - mu) * inv, gp[32+j], bp[32+j]);

            #pragma unroll
            for (int d = 0; d < DH; ++d) a[d] = 0.0f;

            const float* Wl = wmid_l + l*DH*DH;
            #pragma unroll 4
            for (int k = 0; k < 32; ++k) {
                const float hk = myact[k*64];
                const f32x4* wr = (const f32x4*)(Wl + k*DH);
                #pragma unroll
                for (int j = 0; j < 16; ++j) {
                    const f32x4 w4 = wr[j];
                    a[4*j+0] = fmaf(hk, w4.x, a[4*j+0]);
                    a[4*j+1] = fmaf(hk, w4.y, a[4*j+1]);
                    a[4*j+2] = fmaf(hk, w4.z, a[4*j+2]);
                    a[4*j+3] = fmaf(hk, w4.w, a[4*j+3]);
                }
            }
            #pragma unroll
            for (int j = 0; j < 32; ++j)
                myact[j*64] = hh[j];
            #pragma unroll 4
            for (int k = 32; k < DH; ++k) {
                const float hk = myact[(k-32)*64];
                const f32x4* wr = (const f32x4*)(Wl + k*DH);
                #pragma unroll
                for (int j = 0; j < 16; ++j) {
                    const f32x4 w4 = wr[j];
                    a[4*j+0] = fmaf(hk, w4.x, a[4*j+0]);
                    a[4*j+1] = fmaf(hk, w4.y, a[4*j+1]);
                    a[4*j+2] = fmaf(hk, w4.z, a[4*j+2]);
                    a[4*j+3] = fmaf(hk, w4.w, a[4*j+3]);
                }
            }
            const float* bm = b_mid + l*DH;
            #pragma unroll
            for (int d = 0; d < DH; ++d) a[d] += bm[d];
        }

        #pragma unroll
        for (int d = 0; d < DH; ++d) a[d] = fmaxf(a[d], 0.0f);

        float c0 = 0.f, c1 = 0.f, c2 = 0.f, c3 = 0.f;
        float e0 = 0.f, e1 = 0.f, e2 = 0.f, e3 = 0.f;
        #pragma unroll
        for (int j = 0; j < 16; ++j) {
            c0 = fmaf(a[4*j+0], W_cls[4*j+0],  c0);
            c1 = fmaf(a[4*j+1], W_cls[4*j+1],  c1);
            c2 = fmaf(a[4*j+2], W_cls[4*j+2],  c2);
            c3 = fmaf(a[4*j+3], W_cls[4*j+3],  c3);
            e0 = fmaf(a[4*j+0], W_dist[4*j+0], e0);
            e1 = fmaf(a[4*j+1], W_dist[4*j+1], e1);
            e2 = fmaf(a[4*j+2], W_dist[4*j+2], e2);
            e3 = fmaf(a[4*j+3], W_dist[4*j+3], e3);
        }
        float cls = ((c0 + c1) + (c2 + c3)) + b_cls[0];
        float dv  = ((e0 + e1) + (e2 + e3)) + b_dist[0];
        float dval = fmaf(dv, dt, t1i);

        float thr = 2e-6f * invprod;
        thr = fminf(fmaxf(thr, 3e-5f), 2e-2f);
        if ((fabsf(cls) < thr) || (fabsf(dval) < thr)) {
            slow_eval(orig, vec, t1, t2, (size_t)i * R + r, (unsigned)r,
                      W_in, b_in, ln_g, ln_b, W_mid, b_mid,
                      W_cls, b_cls, W_dist, b_dist, cls, dval);
        }

        if (cls > 0.0f && dval < dist) dist = dval;
    }

    const float dfin = (dist == BIGV) ? 0.0f : dist;
    out[r]     = (dfin > 0.0f) ? 1.0f : 0.0f;
    out[R + r] = dfin;
}

extern "C" void kernel_launch(void* const* d_in, const int* in_sizes, int n_in,
                              void* d_out, int out_size, void* d_ws, size_t ws_size,
                              hipStream_t stream) {
    const float* orig   = (const float*)d_in[0];
    const float* vec    = (const float*)d_in[1];
    const float* t1     = (const float*)d_in[2];
    const float* t2     = (const float*)d_in[3];
    const int*   mask   = (const int*)  d_in[4];
    const float* W_in   = (const float*)d_in[5];
    const float* b_in   = (const float*)d_in[6];
    const float* ln_g   = (const float*)d_in[7];
    const float* ln_b   = (const float*)d_in[8];
    const float* W_mid  = (const float*)d_in[9];
    const float* b_mid  = (const float*)d_in[10];
    const float* W_cls  = (const float*)d_in[11];
    const float* b_cls  = (const float*)d_in[12];
    const float* W_dist = (const float*)d_in[13];
    const float* b_dist = (const float*)d_in[14];

    float* out = (float*)d_out;
    const int R = in_sizes[0] / 3;

    const size_t need_ws = 16 + 4ull * (size_t)R * NITER;
    const bool fast = (R == (1 << RLOG)) && (ws_size >= need_ws);

    if (fast) {
        unsigned* cnt   = (unsigned*)d_ws;
        unsigned* work  = (unsigned*)d_ws + 4;   // 16B offset
        unsigned* arena = (unsigned*)d_out + R;  // out[R..2R) as key arena

        hipMemsetAsync(cnt, 0, 4, stream);
        compact_k<<<(R * NITER) / 256, 256, 0, stream>>>(mask, cnt, work);
        prepuv_k<<<2, 256, 0, stream>>>(W_in);
        init_k<<<1024, 256, 0, stream>>>(arena, R);
        main1_k<<<1024, 512, 0, stream>>>(orig, vec, t1, t2,
                                          W_in, b_in, ln_g, ln_b, W_mid, b_mid,
                                          W_cls, b_cls, W_dist, b_dist,
                                          work, cnt, arena);
        finalize_k<<<1024, 256, 0, stream>>>(out, R);
    } else {
        const int threads = 256;
        const int blocks  = (R + threads - 1) / threads;
        fallback_k<<<blocks, threads, 0, stream>>>(
            orig, vec, t1, t2, mask,
            W_in, b_in, ln_g, ln_b, W_mid, b_mid,
            W_cls, b_cls, W_dist, b_dist,
            out, R);
    }
}

// Round 19
// 5199.179 us; speedup vs baseline: 1.7045x; 1.5382x over previous
//
#include <hip/hip_runtime.h>
#include <math.h>

constexpr int   P      = 16;   // N_POINTS
constexpr int   DIN    = 48;   // P*3
constexpr int   DH     = 64;   // hidden dim
constexpr int   NITER  = 8;    // I
constexpr int   NLAYER = 2;    // L
constexpr float BIGV   = 1e9f;
constexpr float INV_R  = 1.0f / 2.5f;
constexpr int   RLOG   = 20;   // fast path requires R == 1<<20

typedef float f32x4 __attribute__((ext_vector_type(4)));
typedef const __attribute__((address_space(1))) f32x4 gf4_t;

// Launder a wave-uniform address onto the VMEM/vmcnt path (validated R4/R7/R8).
__device__ __forceinline__ gf4_t* vmem(const float* p) {
    unsigned long long a = (unsigned long long)p;
    asm volatile("" : "+v"(a));
    return (gf4_t*)a;
}

// monotonic float<->uint key map (total order)
__device__ __forceinline__ unsigned fkey(float f) {
    unsigned b = __float_as_uint(f);
    return (b & 0x80000000u) ? ~b : (b | 0x80000000u);
}
__device__ __forceinline__ float funkey(unsigned k) {
    unsigned b = (k & 0x80000000u) ? (k ^ 0x80000000u) : ~k;
    return __uint_as_float(b);
}

// ---------------------------------------------------------------------------
// SLOW PATH (rare): correctly-rounded f32 elementwise, f64 reductions.
// Verbatim from all passing rounds.
// ---------------------------------------------------------------------------
__device__ __noinline__
void slow_eval(const float* __restrict__ orig, const float* __restrict__ vec,
               const float* __restrict__ t1,   const float* __restrict__ t2,
               size_t tidx, unsigned r,
               const float* __restrict__ W_in,  const float* __restrict__ b_in,
               const float* __restrict__ ln_g,  const float* __restrict__ ln_b,
               const float* __restrict__ W_mid, const float* __restrict__ b_mid,
               const float* __restrict__ W_cls, const float* __restrict__ b_cls,
               const float* __restrict__ W_dist,const float* __restrict__ b_dist,
               float& cls_o, float& dval_o)
{
    const float o0 = orig[3*r+0], o1 = orig[3*r+1], o2 = orig[3*r+2];
    const float v0 = vec[3*r+0],  v1 = vec[3*r+1],  v2 = vec[3*r+2];
    const float t1i = t1[tidx], t2i = t2[tidx];

    const float dt  = __fsub_rn(t2i, t1i);
    const float io0 = __fadd_rn(o0, __fmul_rn(v0, t1i));
    const float io1 = __fadd_rn(o1, __fmul_rn(v1, t1i));
    const float io2 = __fadd_rn(o2, __fmul_rn(v2, t1i));
    const float iv0 = __fmul_rn(v0, dt);
    const float iv1 = __fmul_rn(v1, dt);
    const float iv2 = __fmul_rn(v2, dt);
    const float delta = 1.0f / 15.0f;

    float x[DIN];
    #pragma unroll
    for (int p = 0; p < P; ++p) {
        const float tp = __fmul_rn((float)p, delta);
        x[3*p+0] = __fdiv_rn(__fadd_rn(io0, __fmul_rn(iv0, tp)), 2.5f);
        x[3*p+1] = __fdiv_rn(__fadd_rn(io1, __fmul_rn(iv1, tp)), 2.5f);
        x[3*p+2] = __fdiv_rn(__fadd_rn(io2, __fmul_rn(iv2, tp)), 2.5f);
    }

    float a[DH];
    #pragma unroll 1
    for (int d = 0; d < DH; ++d) {
        double acc0 = 0.0, acc1 = 0.0;
        #pragma unroll
        for (int k = 0; k < DIN; k += 2) {
            acc0 = fma((double)x[k],   (double)W_in[k*DH + d],     acc0);
            acc1 = fma((double)x[k+1], (double)W_in[(k+1)*DH + d], acc1);
        }
        a[d] = __fadd_rn((float)(acc0 + acc1), b_in[d]);
    }

    #pragma unroll 1
    for (int l = 0; l < NLAYER; ++l) {
        #pragma unroll 1
        for (int d = 0; d < DH; ++d) a[d] = fmaxf(a[d], 0.0f);

        double s = 0.0;
        #pragma unroll 1
        for (int d = 0; d < DH; ++d) s += (double)a[d];
        const float mu = (float)(s * (1.0 / 64.0));

        double vs = 0.0;
        #pragma unroll 1
        for (int d = 0; d < DH; ++d) {
            const float c = __fsub_rn(a[d], mu);
            vs = fma((double)c, (double)c, vs);
        }
        const float var = (float)(vs * (1.0 / 64.0));
        const float ve  = __fadd_rn(var, 1e-5f);
        const float inv = (float)(1.0 / sqrt((double)ve));

        float hn[DH];
        #pragma unroll 1
        for (int d = 0; d < DH; ++d) {
            float t = __fsub_rn(a[d], mu);
            t = __fmul_rn(t, inv);
            t = __fmul_rn(t, ln_g[l*DH + d]);
            hn[d] = __fadd_rn(t, ln_b[l*DH + d]);
        }

        #pragma unroll 1
        for (int d = 0; d < DH; ++d) {
            double acc0 = 0.0, acc1 = 0.0;
            #pragma unroll
            for (int k = 0; k < DH; k += 2) {
                acc0 = fma((double)hn[k],   (double)W_mid[(l*DH + k)*DH + d],   acc0);
                acc1 = fma((double)hn[k+1], (double)W_mid[(l*DH + k+1)*DH + d], acc1);
            }
            a[d] = __fadd_rn((float)(acc0 + acc1), b_mid[l*DH + d]);
        }
    }

    double c0 = 0.0, c1 = 0.0, d0 = 0.0, d1 = 0.0;
    #pragma unroll 1
    for (int d = 0; d < DH; d += 2) {
        const float h0 = fmaxf(a[d],   0.0f);
        const float h1 = fmaxf(a[d+1], 0.0f);
        c0 = fma((double)h0, (double)W_cls[d],    c0);
        c1 = fma((double)h1, (double)W_cls[d+1],  c1);
        d0 = fma((double)h0, (double)W_dist[d],   d0);
        d1 = fma((double)h1, (double)W_dist[d+1], d1);
    }
    const float cls = __fadd_rn((float)(c0 + c1), b_cls[0]);
    const float dv  = __fadd_rn((float)(d0 + d1), b_dist[0]);
    cls_o  = cls;
    dval_o = __fadd_rn(__fmul_rn(dv, dt), t1i);
}

// ---------------------------------------------------------------------------
// Compaction: ONE atomic per 256-thread block (validated R14). Worklist order
// changes; results don't (atomicMin order-independent; slow-path per-item).
// ---------------------------------------------------------------------------
__global__ __launch_bounds__(256)
void compact_k(const int* __restrict__ mask, unsigned* __restrict__ cnt,
               unsigned* __restrict__ work)
{
    __shared__ unsigned wcnt[4];
    __shared__ unsigned woff[4];

    const int tid  = threadIdx.x;
    const int lane = tid & 63;
    const int wv   = tid >> 6;
    const int idx  = blockIdx.x * 256 + tid;

    const bool m = (mask[idx] != 0);
    const unsigned long long b = __ballot(m);
    const int nact = __popcll(b);
    if (lane == 0) wcnt[wv] = (unsigned)nact;
    __syncthreads();
    if (tid == 0) {
        const unsigned tot = wcnt[0] + wcnt[1] + wcnt[2] + wcnt[3];
        unsigned base = tot ? atomicAdd(cnt, tot) : 0u;
        #pragma unroll
        for (int w = 0; w < 4; ++w) { woff[w] = base; base += wcnt[w]; }
    }
    __syncthreads();
    if (m) {
        const int pre = __popcll(b & ((1ull << lane) - 1ull));
        work[woff[wv] + pre] = (unsigned)idx;
    }
}

__global__ __launch_bounds__(256)
void init_k(unsigned* __restrict__ arena, int R)
{
    const unsigned key_big = fkey(BIGV);
    for (int r = blockIdx.x * 256 + threadIdx.x; r < R; r += gridDim.x * 256)
        arena[r] = key_big;
}

__global__ __launch_bounds__(256)
void finalize_k(float* __restrict__ out, int R)
{
    unsigned* arena = (unsigned*)out + R;
    for (int r = blockIdx.x * 256 + threadIdx.x; r < R; r += gridDim.x * 256) {
        const float dist = funkey(arena[r]);
        const float dfin = (dist == BIGV) ? 0.0f : dist;
        out[r] = (dfin > 0.0f) ? 1.0f : 0.0f;
        ((float*)arena)[r] = dfin;
    }
}

// ---------------------------------------------------------------------------
// k-half matmul, 1 item per lane. Inner fmaf order identical to the
// validated R5/R13 body (k sequential, per component).
// ---------------------------------------------------------------------------
template<bool GLOBAL>
__device__ __forceinline__
void mm_khalf1(const float* Wbase, int kofs, const float* col, float (&a)[DH])
{
    #pragma unroll 2
    for (int k = 0; k < 32; ++k) {
        const float hk = col[k*64];
        if constexpr (GLOBAL) {
            gf4_t* wr = vmem(Wbase + (kofs + k)*DH);
            #pragma unroll
            for (int j = 0; j < 16; ++j) {
                const f32x4 w4 = wr[j];
                a[4*j+0] = fmaf(hk, w4.x, a[4*j+0]);
                a[4*j+1] = fmaf(hk, w4.y, a[4*j+1]);
                a[4*j+2] = fmaf(hk, w4.z, a[4*j+2]);
                a[4*j+3] = fmaf(hk, w4.w, a[4*j+3]);
            }
        } else {
            const f32x4* wr = (const f32x4*)(Wbase + (kofs + k)*DH);
            #pragma unroll
            for (int j = 0; j < 16; ++j) {
                const f32x4 w4 = wr[j];
                a[4*j+0] = fmaf(hk, w4.x, a[4*j+0]);
                a[4*j+1] = fmaf(hk, w4.y, a[4*j+1]);
                a[4*j+2] = fmaf(hk, w4.z, a[4*j+2]);
                a[4*j+3] = fmaf(hk, w4.w, a[4*j+3]);
            }
        }
    }
}

// ---------------------------------------------------------------------------
// MAIN (best-measured configuration, R14: 5255 us total): 256 threads
// (4 waves), ONE item/lane, __launch_bounds__(256, 3). LDS = act[4][32][64]
// (32 KB) + W_mid layer-0 (16 KB) = 48 KB. Layer-1 weights + W_in ride the
// vmcnt pipe. Per-item FP sequence identical to validated R5/R13
// (absmax 0.00390625).
// ---------------------------------------------------------------------------
__global__ __launch_bounds__(256, 3)
void main1_k(const float* __restrict__ orig,
             const float* __restrict__ vec,
             const float* __restrict__ t1,
             const float* __restrict__ t2,
             const float* __restrict__ W_in,
             const float* __restrict__ b_in,
             const float* __restrict__ ln_g,
             const float* __restrict__ ln_b,
             const float* __restrict__ W_mid,
             const float* __restrict__ b_mid,
             const float* __restrict__ W_cls,
             const float* __restrict__ b_cls,
             const float* __restrict__ W_dist,
             const float* __restrict__ b_dist,
             const unsigned* __restrict__ work,
             const unsigned* __restrict__ cnt,
             unsigned* __restrict__ arena)
{
    __shared__ __align__(16) float wl0[DH*DH];      // 16 KiB: W_mid layer 0
    __shared__ __align__(16) float act[4][32][64];  // 32 KiB

    const int tid  = threadIdx.x;
    const int lane = tid & 63;
    const int wv   = tid >> 6;

    {   // stage W_mid layer 0 (whole block), one barrier
        f32x4*       dst = (f32x4*)wl0;
        const f32x4* s2  = (const f32x4*)W_mid;
        #pragma unroll 1
        for (int idx = tid; idx < DH*DH/4; idx += 256) dst[idx] = s2[idx];
    }
    __syncthreads();

    float* col = &act[wv][0][lane];   // element k lives at col[k*64]

    const unsigned T    = *cnt;
    const unsigned gtid = blockIdx.x * 256 + tid;
    const unsigned NTOT = gridDim.x * 256;

    for (unsigned g = gtid; g < T; g += NTOT) {
        const unsigned pk = work[g];
        const unsigned r  = pk & 0xFFFFFu;
        const float tt1 = t1[pk], tt2 = t2[pk];
        const float dt  = tt2 - tt1;
        const float o0 = orig[3*r+0], o1 = orig[3*r+1], o2 = orig[3*r+2];
        const float v0 = vec[3*r+0],  v1 = vec[3*r+1],  v2 = vec[3*r+2];
        const float io0 = fmaf(v0, tt1, o0);
        const float io1 = fmaf(v1, tt1, o1);
        const float io2 = fmaf(v2, tt1, o2);
        const float iv0 = v0 * dt, iv1 = v1 * dt, iv2 = v2 * dt;

        float a[DH];
        #pragma unroll
        for (int d = 0; d < DH; ++d) a[d] = 0.0f;

        // ---- input layer: x inline; W_in rows via vmcnt pipe (L1)
        #pragma unroll 1
        for (int p = 0; p < P; ++p) {
            const float tp = (float)p * (1.0f / 15.0f);
            const float x0 = fmaf(iv0, tp, io0) * INV_R;
            const float x1 = fmaf(iv1, tp, io1) * INV_R;
            const float x2 = fmaf(iv2, tp, io2) * INV_R;
            gf4_t* w0 = vmem(W_in + (3*p+0)*DH);
            gf4_t* w1 = vmem(W_in + (3*p+1)*DH);
            gf4_t* w2 = vmem(W_in + (3*p+2)*DH);
            #pragma unroll
            for (int j = 0; j < 16; ++j) {
                const f32x4 u = w0[j], v4 = w1[j], w4 = w2[j];
                a[4*j+0] = fmaf(x2, w4.x, fmaf(x1, v4.x, fmaf(x0, u.x, a[4*j+0])));
                a[4*j+1] = fmaf(x2, w4.y, fmaf(x1, v4.y, fmaf(x0, u.y, a[4*j+1])));
                a[4*j+2] = fmaf(x2, w4.z, fmaf(x1, v4.z, fmaf(x0, u.z, a[4*j+2])));
                a[4*j+3] = fmaf(x2, w4.w, fmaf(x1, v4.w, fmaf(x0, u.w, a[4*j+3])));
            }
        }
        #pragma unroll
        for (int d = 0; d < DH; ++d) a[d] += b_in[d];

        float invprod = 1.0f;

        // ---- mid layers: relu -> LN -> k-halved matmul
        // layer 0 weights: LDS (wl0). layer 1 weights: vmem (L1/L2).
        #pragma unroll
        for (int l = 0; l < NLAYER; ++l) {
            #pragma unroll
            for (int d = 0; d < DH; ++d) a[d] = fmaxf(a[d], 0.0f);

            float mu = 0.0f;
            #pragma unroll
            for (int d = 0; d < DH; ++d) mu += a[d];
            mu *= (1.0f / 64.0f);

            float var = 0.0f;
            #pragma unroll
            for (int d = 0; d < DH; ++d) {
                const float c = a[d] - mu;
                var = fmaf(c, c, var);
            }
            var *= (1.0f / 64.0f);
            const float inv = 1.0f / sqrtf(var + 1e-5f);
            invprod *= inv;

            const float* gg = ln_g + l*DH;
            const float* bb = ln_b + l*DH;

            // lower half of hn -> LDS column; upper half -> 32 temp regs
            #pragma unroll
            for (int d = 0; d < 32; ++d)
                col[d*64] = fmaf((a[d] - mu) * inv, gg[d], bb[d]);
            float hh[32];
            #pragma unroll
            for (int j = 0; j < 32; ++j)
                hh[j] = fmaf((a[32+j] - mu) * inv, gg[32+j], bb[32+j]);

            #pragma unroll
            for (int d = 0; d < DH; ++d) a[d] = 0.0f;

            if (l == 0) mm_khalf1<false>(wl0,            0, col, a);
            else        mm_khalf1<true >(W_mid + DH*DH,  0, col, a);

            #pragma unroll
            for (int j = 0; j < 32; ++j)    // park upper half (in-order DS)
                col[j*64] = hh[j];

            if (l == 0) mm_khalf1<false>(wl0,           32, col, a);
            else        mm_khalf1<true >(W_mid + DH*DH, 32, col, a);

            const float* bm = b_mid + l*DH;
            #pragma unroll
            for (int d = 0; d < DH; ++d) a[d] += bm[d];
        }

        // ---- heads (4 chains each, identical to validated rounds)
        #pragma unroll
        for (int d = 0; d < DH; ++d) a[d] = fmaxf(a[d], 0.0f);

        float c0 = 0.f, c1 = 0.f, c2 = 0.f, c3 = 0.f;
        float e0 = 0.f, e1 = 0.f, e2 = 0.f, e3 = 0.f;
        #pragma unroll
        for (int j = 0; j < 16; ++j) {
            c0 = fmaf(a[4*j+0], W_cls[4*j+0],  c0);
            c1 = fmaf(a[4*j+1], W_cls[4*j+1],  c1);
            c2 = fmaf(a[4*j+2], W_cls[4*j+2],  c2);
            c3 = fmaf(a[4*j+3], W_cls[4*j+3],  c3);
            e0 = fmaf(a[4*j+0], W_dist[4*j+0], e0);
            e1 = fmaf(a[4*j+1], W_dist[4*j+1], e1);
            e2 = fmaf(a[4*j+2], W_dist[4*j+2], e2);
            e3 = fmaf(a[4*j+3], W_dist[4*j+3], e3);
        }
        float cls = ((c0 + c1) + (c2 + c3)) + b_cls[0];
        float dv  = ((e0 + e1) + (e2 + e3)) + b_dist[0];
        float dval = fmaf(dv, dt, tt1);

        float thr = 2e-6f * invprod;
        thr = fminf(fmaxf(thr, 3e-5f), 2e-2f);
        if ((fabsf(cls) < thr) || (fabsf(dval) < thr)) {
            slow_eval(orig, vec, t1, t2, (size_t)pk, r,
                      W_in, b_in, ln_g, ln_b, W_mid, b_mid,
                      W_cls, b_cls, W_dist, b_dist, cls, dval);
        }
        if (cls > 0.0f)
            atomicMin(arena + r, fkey(dval));
    }
}

// ---------------------------------------------------------------------------
// FALLBACK (round-5 kernel, known-good) for unexpected R / small workspace.
// ---------------------------------------------------------------------------
__global__ __launch_bounds__(256, 2)
void fallback_k(const float* __restrict__ orig, const float* __restrict__ vec,
                const float* __restrict__ t1,   const float* __restrict__ t2,
                const int*   __restrict__ mask,
                const float* __restrict__ W_in,  const float* __restrict__ b_in,
                const float* __restrict__ ln_g,  const float* __restrict__ ln_b,
                const float* __restrict__ W_mid, const float* __restrict__ b_mid,
                const float* __restrict__ W_cls, const float* __restrict__ b_cls,
                const float* __restrict__ W_dist,const float* __restrict__ b_dist,
                float* __restrict__ out, int R)
{
    __shared__ __align__(16) float wlds[DIN*DH + NLAYER*DH*DH];
    __shared__ __align__(16) float act[4][32][64];

    const int tid  = threadIdx.x;
    const int lane = tid & 63;
    const int wv   = tid >> 6;

    {
        f32x4*       dst = (f32x4*)wlds;
        const f32x4* s1  = (const f32x4*)W_in;
        const f32x4* s2  = (const f32x4*)W_mid;
        #pragma unroll 1
        for (int idx = tid; idx < DIN*DH/4; idx += 256)        dst[idx] = s1[idx];
        #pragma unroll 1
        for (int idx = tid; idx < NLAYER*DH*DH/4; idx += 256)  dst[DIN*DH/4 + idx] = s2[idx];
    }
    __syncthreads();

    const float* win_l  = wlds;
    const float* wmid_l = wlds + DIN*DH;

    const int r = blockIdx.x * 256 + tid;
    if (r >= R) return;

    float* myact = &act[wv][0][lane];

    const float o0 = orig[3*r+0], o1 = orig[3*r+1], o2 = orig[3*r+2];
    const float v0 = vec[3*r+0],  v1 = vec[3*r+1],  v2 = vec[3*r+2];

    float dist = BIGV;

    #pragma unroll 1
    for (int i = 0; i < NITER; ++i) {
        const float t1i = t1[(size_t)i * R + r];
        const float t2i = t2[(size_t)i * R + r];
        const int   mi  = mask[(size_t)i * R + r];
        if (!mi) continue;
        const float dt = t2i - t1i;

        const float io0 = fmaf(v0, t1i, o0);
        const float io1 = fmaf(v1, t1i, o1);
        const float io2 = fmaf(v2, t1i, o2);
        const float iv0 = v0 * dt, iv1 = v1 * dt, iv2 = v2 * dt;

        float a[DH];
        #pragma unroll
        for (int d = 0; d < DH; ++d) a[d] = 0.0f;

        #pragma unroll 1
        for (int p = 0; p < P; ++p) {
            const float tp = (float)p * (1.0f / 15.0f);
            const float x0 = fmaf(iv0, tp, io0) * INV_R;
            const float x1 = fmaf(iv1, tp, io1) * INV_R;
            const float x2 = fmaf(iv2, tp, io2) * INV_R;
            const f32x4* w0 = (const f32x4*)(win_l + (3*p+0)*DH);
            const f32x4* w1 = (const f32x4*)(win_l + (3*p+1)*DH);
            const f32x4* w2 = (const f32x4*)(win_l + (3*p+2)*DH);
            #pragma unroll
            for (int j = 0; j < 16; ++j) {
                const f32x4 u = w0[j], v4 = w1[j], w4 = w2[j];
                a[4*j+0] = fmaf(x2, w4.x, fmaf(x1, v4.x, fmaf(x0, u.x, a[4*j+0])));
                a[4*j+1] = fmaf(x2, w4.y, fmaf(x1, v4.y, fmaf(x0, u.y, a[4*j+1])));
                a[4*j+2] = fmaf(x2, w4.z, fmaf(x1, v4.z, fmaf(x0, u.z, a[4*j+2])));
                a[4*j+3] = fmaf(x2, w4.w, fmaf(x1, v4.w, fmaf(x0, u.w, a[4*j+3])));
            }
        }
        #pragma unroll
        for (int d = 0; d < DH; ++d) a[d] += b_in[d];

        float invprod = 1.0f;

        #pragma unroll 1
        for (int l = 0; l < NLAYER; ++l) {
            #pragma unroll
            for (int d = 0; d < DH; ++d) a[d] = fmaxf(a[d], 0.0f);

            float mu = 0.0f;
            #pragma unroll
            for (int d = 0; d < DH; ++d) mu += a[d];
            mu *= (1.0f / 64.0f);

            float var = 0.0f;
            #pragma unroll
            for (int d = 0; d < DH; ++d) {
                const float cdev = a[d] - mu;
                var = fmaf(cdev, cdev, var);
            }
            var *= (1.0f / 64.0f);
            const float inv = 1.0f / sqrtf(var + 1e-5f);
            invprod *= inv;

            const float* gp = ln_g + l*DH;
            const float* bp = ln_b + l*DH;

            #pragma unroll
            for (int d = 0; d < 32; ++d)
                myact[d*64] = fmaf((a[d] - mu) * inv, gp[d], bp[d]);
            float hh[32];
            #pragma unroll
            for (int j = 0; j < 32; ++j)
                hh[j] = fmaf((a[32+j] - mu) * inv, gp[32+j], bp[32+j]);

            #pragma unroll
            for (int d = 0; d < DH; ++d) a[d] = 0.0f;

            const float* Wl = wmid_l + l*DH*DH;
            #pragma unroll 4
            for (int k = 0; k < 32; ++k) {
                const float hk = myact[k*64];
                const f32x4* wr = (const f32x4*)(Wl + k*DH);
                #pragma unroll
                for (int j = 0; j < 16; ++j) {
                    const f32x4 w4 = wr[j];
                    a[4*j+0] = fmaf(hk, w4.x, a[4*j+0]);
                    a[4*j+1] = fmaf(hk, w4.y, a[4*j+1]);
                    a[4*j+2] = fmaf(hk, w4.z, a[4*j+2]);
                    a[4*j+3] = fmaf(hk, w4.w, a[4*j+3]);
                }
            }
            #pragma unroll
            for (int j = 0; j < 32; ++j)
                myact[j*64] = hh[j];
            #pragma unroll 4
            for (int k = 32; k < DH; ++k) {
                const float hk = myact[(k-32)*64];
                const f32x4* wr = (const f32x4*)(Wl + k*DH);
                #pragma unroll
                for (int j = 0; j < 16; ++j) {
                    const f32x4 w4 = wr[j];
                    a[4*j+0] = fmaf(hk, w4.x, a[4*j+0]);
                    a[4*j+1] = fmaf(hk, w4.y, a[4*j+1]);
                    a[4*j+2] = fmaf(hk, w4.z, a[4*j+2]);
                    a[4*j+3] = fmaf(hk, w4.w, a[4*j+3]);
                }
            }
            const float* bm = b_mid + l*DH;
            #pragma unroll
            for (int d = 0; d < DH; ++d) a[d] += bm[d];
        }

        #pragma unroll
        for (int d = 0; d < DH; ++d) a[d] = fmaxf(a[d], 0.0f);

        float c0 = 0.f, c1 = 0.f, c2 = 0.f, c3 = 0.f;
        float e0 = 0.f, e1 = 0.f, e2 = 0.f, e3 = 0.f;
        #pragma unroll
        for (int j = 0; j < 16; ++j) {
            c0 = fmaf(a[4*j+0], W_cls[4*j+0],  c0);
            c1 = fmaf(a[4*j+1], W_cls[4*j+1],  c1);
            c2 = fmaf(a[4*j+2], W_cls[4*j+2],  c2);
            c3 = fmaf(a[4*j+3], W_cls[4*j+3],  c3);
            e0 = fmaf(a[4*j+0], W_dist[4*j+0], e0);
            e1 = fmaf(a[4*j+1], W_dist[4*j+1], e1);
            e2 = fmaf(a[4*j+2], W_dist[4*j+2], e2);
            e3 = fmaf(a[4*j+3], W_dist[4*j+3], e3);
        }
        float cls = ((c0 + c1) + (c2 + c3)) + b_cls[0];
        float dv  = ((e0 + e1) + (e2 + e3)) + b_dist[0];
        float dval = fmaf(dv, dt, t1i);

        float thr = 2e-6f * invprod;
        thr = fminf(fmaxf(thr, 3e-5f), 2e-2f);
        if ((fabsf(cls) < thr) || (fabsf(dval) < thr)) {
            slow_eval(orig, vec, t1, t2, (size_t)i * R + r, (unsigned)r,
                      W_in, b_in, ln_g, ln_b, W_mid, b_mid,
                      W_cls, b_cls, W_dist, b_dist, cls, dval);
        }

        if (cls > 0.0f && dval < dist) dist = dval;
    }

    const float dfin = (dist == BIGV) ? 0.0f : dist;
    out[r]     = (dfin > 0.0f) ? 1.0f : 0.0f;
    out[R + r] = dfin;
}

extern "C" void kernel_launch(void* const* d_in, const int* in_sizes, int n_in,
                              void* d_out, int out_size, void* d_ws, size_t ws_size,
                              hipStream_t stream) {
    const float* orig   = (const float*)d_in[0];
    const float* vec    = (const float*)d_in[1];
    const float* t1     = (const float*)d_in[2];
    const float* t2     = (const float*)d_in[3];
    const int*   mask   = (const int*)  d_in[4];
    const float* W_in   = (const float*)d_in[5];
    const float* b_in   = (const float*)d_in[6];
    const float* ln_g   = (const float*)d_in[7];
    const float* ln_b   = (const float*)d_in[8];
    const float* W_mid  = (const float*)d_in[9];
    const float* b_mid  = (const float*)d_in[10];
    const float* W_cls  = (const float*)d_in[11];
    const float* b_cls  = (const float*)d_in[12];
    const float* W_dist = (const float*)d_in[13];
    const float* b_dist = (const float*)d_in[14];

    float* out = (float*)d_out;
    const int R = in_sizes[0] / 3;

    const size_t need_ws = 16 + 4ull * (size_t)R * NITER;
    const bool fast = (R == (1 << RLOG)) && (ws_size >= need_ws);

    if (fast) {
        unsigned* cnt   = (unsigned*)d_ws;
        unsigned* work  = (unsigned*)d_ws + 4;   // 16B offset
        unsigned* arena = (unsigned*)d_out + R;  // out[R..2R) as key arena

        hipMemsetAsync(cnt, 0, 4, stream);
        compact_k<<<(R * NITER) / 256, 256, 0, stream>>>(mask, cnt, work);
        init_k<<<1024, 256, 0, stream>>>(arena, R);
        main1_k<<<4096, 256, 0, stream>>>(orig, vec, t1, t2,
                                          W_in, b_in, ln_g, ln_b, W_mid, b_mid,
                                          W_cls, b_cls, W_dist, b_dist,
                                          work, cnt, arena);
        finalize_k<<<1024, 256, 0, stream>>>(out, R);
    } else {
        const int threads = 256;
        const int blocks  = (R + threads - 1) / threads;
        fallback_k<<<blocks, threads, 0, stream>>>(
            orig, vec, t1, t2, mask,
            W_in, b_in, ln_g, ln_b, W_mid, b_mid,
            W_cls, b_cls, W_dist, b_dist,
            out, R);
    }
}